// Round 6
// baseline (433.656 us; speedup 1.0000x reference)
//
#include <hip/hip_runtime.h>
#include <hip/hip_bf16.h>
#include <stdint.h>

// Problem constants (fixed by setup_inputs)
#define B_   64
#define H_   512
#define W_   512
#define S_N  1024      // n_segments
#define E_N  768       // embed_dim
#define K_N  768       // C*box*box = 3*16*16
#define HALF 8

typedef short bf16x8 __attribute__((ext_vector_type(8)));
typedef float f32x4  __attribute__((ext_vector_type(4)));

__device__ __forceinline__ unsigned short f2bf(float f) {
  union { float f; unsigned u; } v; v.f = f;
  unsigned u = v.u;
  u += 0x7FFF + ((u >> 16) & 1);   // RNE
  return (unsigned short)(u >> 16);
}

// ---------------- conv_w fp32 -> bf16, float4 loads ----------
__global__ void k_convw(const float* __restrict__ w, unsigned short* __restrict__ wb) {
  int idx = blockIdx.x * 256 + threadIdx.x;   // 147,456 float4s
  float4 v = ((const float4*)w)[idx];
  ushort4 o;
  o.x = f2bf(v.x); o.y = f2bf(v.y); o.z = f2bf(v.z); o.w = f2bf(v.w);
  ((ushort4*)wb)[idx] = o;
}

// ---------------- Phase 1: per-(b,s) packed sums, NO global atomics -----------
// [y:24 @39 | x:24 @15 | cnt:15 @0]; per-block maxima can't cross fields.
__global__ void k_accum2(const int* __restrict__ seg,
                         unsigned long long* __restrict__ partials) {
  __shared__ unsigned long long ls[S_N];
  const int tid = threadIdx.x;
  const int xblk = blockIdx.x;   // 0..15
  const int b = blockIdx.y;
  for (int i = tid; i < S_N; i += 256) ls[i] = 0ULL;
  __syncthreads();
  const int pix0 = xblk * 16384;
  const int4* segb = (const int4*)(seg + (size_t)b * (H_ * W_) + pix0);
  for (int it = 0; it < 16; ++it) {
    int4 s4 = segb[it * 256 + tid];
    int p = pix0 + (it * 256 + tid) * 4;
    #pragma unroll
    for (int j = 0; j < 4; ++j) {
      int s = (&s4.x)[j];
      s = ((unsigned)s < S_N) ? s : 0;
      unsigned long long x = (unsigned)((p + j) & (W_ - 1));
      unsigned long long y = (unsigned)((p + j) >> 9);
      atomicAdd(&ls[s], (y << 39) | (x << 15) | 1ULL);
    }
  }
  __syncthreads();
  unsigned long long* gp = partials + ((size_t)b * 16 + xblk) * S_N;
  for (int s = tid; s < S_N; s += 256) gp[s] = ls[s];
}

// ---------------- Phase 2: reduce 16 partials, centroid -> (x_min, y_min) -----
__global__ void k_coords2(const unsigned long long* __restrict__ partials,
                          int2* __restrict__ coords) {
  int m = blockIdx.x * 256 + threadIdx.x;   // 65536 = B*S
  int b = m >> 10, s = m & (S_N - 1);
  unsigned sx = 0, sy = 0, c = 0;
  #pragma unroll
  for (int x = 0; x < 16; ++x) {
    unsigned long long v = partials[((size_t)b * 16 + x) * S_N + s];
    c  += (unsigned)(v & 0x7FFFULL);
    sx += (unsigned)((v >> 15) & 0xFFFFFFULL);
    sy += (unsigned)(v >> 39);
  }
  float xc = 0.f, yc = 0.f;
  if (c > 0) {
    float cf = (float)c;
    xc = (float)sx / cf;   // IEEE f32 div of exact ints == reference
    yc = (float)sy / cf;
  }
  coords[m] = make_int2((int)floorf(xc), (int)floorf(yc));
}

// -------- Phase 3: FUSED gather + 256x256 8-phase bf16 MFMA GEMM --------------
// A is never materialized: each A half-tile is gathered from img (L2-resident
// center region) into registers ONE PHASE EARLY (T14: latency hides under the
// intervening MFMA phase + barriers), then f2bf'd and ds_write_b128'd with the
// T2 swizzle in the phase where the old global_load_lds stageA sat. B keeps
// global_load_lds + counted vmcnt. Last iteration peeled with a full drain
// (fixes the latent tail race of the previous schedule).
__global__ __launch_bounds__(512) void k_gemmf(
    const float* __restrict__ img,
    const int2* __restrict__ coords,
    const unsigned short* __restrict__ Bmat,
    float* __restrict__ out) {
  __shared__ unsigned short As[2][256 * 64];
  __shared__ unsigned short Bs[2][256 * 64];
  const int tid  = threadIdx.x;
  const int wave = tid >> 6;
  const int lane = tid & 63;

  // bijective XCD remap: 768 blocks = 8 XCDs x 96
  const int virt = (blockIdx.x & 7) * 96 + (blockIdx.x >> 3);
  const int bm = virt / 3;
  const int bn = virt - bm * 3;
  const int gm0 = bm * 256;
  const int gn0 = bn * 256;

  const int wr = wave >> 2;          // 0..1
  const int wc = wave & 3;           // 0..3
  const int rlo  = lane & 15;
  const int rsel = lane & 7;
  const int sub  = lane >> 4;        // 0..3
  int swz[2];
  swz[0] = ((0 + sub) ^ rsel) * 8;
  swz[1] = ((4 + sub) ^ rsel) * 8;

  // B staging lane constants (global_load_lds, pre-swizzled source)
  const int srow = lane >> 3;
  const int sch  = (lane & 7) ^ srow;

  // A gather context: thread covers rows row(mh,q) = mh*64 + (tid>>3) + q*128,
  // chunk cc0 = tid&7 (8 bf16 = one (c,h) half-row of the 16x16 patch).
  const int cc0 = tid & 7;
  const int rbase = tid >> 3;        // 0..63
  int   gcoff[2][2];                 // img element offset of (b,c=0,y=0,x=0)
  int   gcx[2][2], gcy[2][2];
  #pragma unroll
  for (int mh = 0; mh < 2; ++mh)
    #pragma unroll
    for (int q = 0; q < 2; ++q) {
      int row = mh * 64 + rbase + q * 128;
      int m = gm0 + row;
      int2 cc = coords[m];
      gcoff[mh][q] = (m >> 10) * 3 * H_ * W_;
      gcx[mh][q] = cc.x - HALF;
      gcy[mh][q] = cc.y - HALF;
    }

#define GATHER(G, MH, K0) do {                                                 \
    const int k_ = (K0) + cc0 * 8;                                             \
    const int c_ = k_ >> 8, h_ = (k_ >> 4) & 15, wh_ = k_ & 15;                \
    _Pragma("unroll") for (int q = 0; q < 2; ++q) {                            \
      int y_ = gcy[MH][q] + h_;                                                \
      int x0_ = gcx[MH][q] + wh_;                                              \
      bool yok_ = ((unsigned)y_ < H_);                                         \
      const float* rp_ = img + gcoff[MH][q] + (((c_ << 9) + (yok_ ? y_ : 0)) << 9); \
      _Pragma("unroll") for (int j = 0; j < 8; ++j) {                          \
        int x_ = x0_ + j;                                                      \
        G[q * 8 + j] = (yok_ && (unsigned)x_ < W_) ? rp_[x_] : 0.f;            \
      }                                                                        \
    }                                                                          \
  } while (0)

#define WRITEA(G, BUF, MH) do {                                                \
    _Pragma("unroll") for (int q = 0; q < 2; ++q) {                            \
      const int row_ = (MH) * 64 + rbase + q * 128;                            \
      bf16x8 t_;                                                               \
      _Pragma("unroll") for (int j = 0; j < 8; ++j)                            \
        t_[j] = (short)f2bf(G[q * 8 + j]);                                     \
      *(bf16x8*)&As[BUF][row_ * 64 + ((cc0 ^ (row_ & 7)) << 3)] = t_;          \
    }                                                                          \
  } while (0)

  f32x4 acc[8][4];
  #pragma unroll
  for (int i = 0; i < 8; ++i)
    #pragma unroll
    for (int j = 0; j < 4; ++j)
      acc[i][j] = (f32x4){0.f, 0.f, 0.f, 0.f};

  auto stageB = [&](int buf, int nh, int k0) {
    #pragma unroll
    for (int l = 0; l < 2; ++l) {
      int idx = wave * 2 + l;
      int rowbase = (idx >> 2) * 64 + nh * 32 + (idx & 3) * 8;
      const unsigned short* g = Bmat + (size_t)(gn0 + rowbase + srow) * K_N + k0 + sch * 8;
      __builtin_amdgcn_global_load_lds((const __attribute__((address_space(1))) void*)g,
        (__attribute__((address_space(3))) void*)&Bs[buf][rowbase * 64], 16, 0, 0);
    }
  };

  bf16x8 a[4][2], b[2][2];
  float g1[16], g2[16];

#define LOAD_A(BUF, MH) \
  _Pragma("unroll") for (int mi = 0; mi < 4; ++mi) \
  _Pragma("unroll") for (int kk = 0; kk < 2; ++kk) \
    a[mi][kk] = *(const bf16x8*)&As[BUF][(wr * 128 + (MH) * 64 + mi * 16 + rlo) * 64 + swz[kk]];
#define LOAD_B(BUF, NH) \
  _Pragma("unroll") for (int ni = 0; ni < 2; ++ni) \
  _Pragma("unroll") for (int kk = 0; kk < 2; ++kk) \
    b[ni][kk] = *(const bf16x8*)&Bs[BUF][(wc * 64 + (NH) * 32 + ni * 16 + rlo) * 64 + swz[kk]];
#define MFMA_Q(MI0, NI0) \
  __builtin_amdgcn_s_setprio(1); \
  _Pragma("unroll") for (int mi = 0; mi < 4; ++mi) \
  _Pragma("unroll") for (int ni = 0; ni < 2; ++ni) \
  _Pragma("unroll") for (int kk = 0; kk < 2; ++kk) \
    acc[(MI0) + mi][(NI0) + ni] = __builtin_amdgcn_mfma_f32_16x16x32_bf16( \
        a[mi][kk], b[ni][kk], acc[(MI0) + mi][(NI0) + ni], 0, 0, 0); \
  __builtin_amdgcn_s_setprio(0);
#define SYNC_MFMA \
  __builtin_amdgcn_s_barrier(); \
  asm volatile("s_waitcnt lgkmcnt(0)" ::: "memory"); \
  __builtin_amdgcn_sched_barrier(0);
#define ENDPH __builtin_amdgcn_s_barrier();

  // ---- Prologue: A tile0 (both halves) + A tile1.h0 gathered & written;
  //      B tile0 (both halves) + B tile1.h1 via global_load_lds.
  GATHER(g1, 0, 0);   WRITEA(g1, 0, 0);
  GATHER(g1, 1, 0);   WRITEA(g1, 0, 1);
  GATHER(g1, 0, 64);  WRITEA(g1, 1, 0);
  stageB(0, 0, 0); stageB(0, 1, 0); stageB(1, 1, 64);
  asm volatile("s_waitcnt vmcnt(2) lgkmcnt(0)" ::: "memory");  // buf0 B landed; our ds_writes drained
  __builtin_amdgcn_s_barrier();

  for (int i = 0; i < 5; ++i) {
    const int kB = (2 * i + 1) * 64;
    const int kC = (2 * i + 2) * 64;
    const int kD = (2 * i + 3) * 64;
    // P1: Q(0,0) of tile 2i (buf0); gather A for buf1.h1 (tile 2i+1)
    GATHER(g1, 1, kB);
    LOAD_A(0, 0); LOAD_B(0, 0);
    stageB(1, 0, kB);
    SYNC_MFMA; MFMA_Q(0, 0); ENDPH;
    // P2: write buf1.h1; gather A for buf0.h0 (tile 2i+2)
    GATHER(g2, 0, kC);
    WRITEA(g1, 1, 1);
    LOAD_B(0, 1);
    SYNC_MFMA; MFMA_Q(0, 2); ENDPH;
    // P3: write buf0.h0
    WRITEA(g2, 0, 0);
    LOAD_A(0, 1);
    SYNC_MFMA; MFMA_Q(4, 2); ENDPH;
    // P4
    LOAD_B(0, 0);
    stageB(0, 1, kC);
    asm volatile("s_waitcnt vmcnt(2)" ::: "memory");   // tile 2i+1 B landed
    SYNC_MFMA; MFMA_Q(4, 0); ENDPH;
    // P5: tile 2i+1 (buf1); gather A for buf0.h1 (tile 2i+2)
    GATHER(g1, 1, kC);
    LOAD_A(1, 0); LOAD_B(1, 0);
    stageB(0, 0, kC);
    SYNC_MFMA; MFMA_Q(0, 0); ENDPH;
    // P6: write buf0.h1; gather A for buf1.h0 (tile 2i+3)
    GATHER(g2, 0, kD);
    WRITEA(g1, 0, 1);
    LOAD_B(1, 1);
    SYNC_MFMA; MFMA_Q(0, 2); ENDPH;
    // P7: write buf1.h0
    WRITEA(g2, 1, 0);
    LOAD_A(1, 1);
    SYNC_MFMA; MFMA_Q(4, 2); ENDPH;
    // P8
    LOAD_B(1, 0);
    stageB(1, 1, kD);
    asm volatile("s_waitcnt vmcnt(2)" ::: "memory");   // tile 2i+2 B landed
    SYNC_MFMA; MFMA_Q(4, 0); ENDPH;
  }

  // ---- Tail: tiles 10 (buf0) and 11 (buf1); no further prefetch.
  {
    const int kB = 11 * 64;
    // P1
    GATHER(g1, 1, kB);
    LOAD_A(0, 0); LOAD_B(0, 0);
    stageB(1, 0, kB);
    SYNC_MFMA; MFMA_Q(0, 0); ENDPH;
    // P2
    WRITEA(g1, 1, 1);
    LOAD_B(0, 1);
    SYNC_MFMA; MFMA_Q(0, 2); ENDPH;
    // P3
    LOAD_A(0, 1);
    SYNC_MFMA; MFMA_Q(4, 2); ENDPH;
    // P4: full drain (no younger stages to count against)
    LOAD_B(0, 0);
    asm volatile("s_waitcnt vmcnt(0)" ::: "memory");
    SYNC_MFMA; MFMA_Q(4, 0); ENDPH;
    // P5
    LOAD_A(1, 0); LOAD_B(1, 0);
    SYNC_MFMA; MFMA_Q(0, 0); ENDPH;
    // P6
    LOAD_B(1, 1);
    SYNC_MFMA; MFMA_Q(0, 2); ENDPH;
    // P7
    LOAD_A(1, 1);
    SYNC_MFMA; MFMA_Q(4, 2); ENDPH;
    // P8
    LOAD_B(1, 0);
    SYNC_MFMA; MFMA_Q(4, 0); ENDPH;
  }

  // Epilogue: C/D layout col=lane&15, row=(lane>>4)*4+reg
  const int row0 = gm0 + wr * 128 + (lane >> 4) * 4;
  const int col0 = gn0 + wc * 64 + (lane & 15);
  #pragma unroll
  for (int mi = 0; mi < 8; ++mi)
    #pragma unroll
    for (int ni = 0; ni < 4; ++ni)
      #pragma unroll
      for (int r = 0; r < 4; ++r)
        out[(size_t)(row0 + mi * 16 + r) * E_N + (col0 + ni * 16)] = acc[mi][ni][r];
#undef LOAD_A
#undef LOAD_B
#undef MFMA_Q
#undef SYNC_MFMA
#undef ENDPH
#undef GATHER
#undef WRITEA
}

extern "C" void kernel_launch(void* const* d_in, const int* in_sizes, int n_in,
                              void* d_out, int out_size, void* d_ws, size_t ws_size,
                              hipStream_t stream) {
  const float* img = (const float*)d_in[0];
  const int*   seg = (const int*)d_in[1];
  const float* cw  = (const float*)d_in[2];
  float* out = (float*)d_out;
  char* ws = (char*)d_ws;

  unsigned long long* partials = (unsigned long long*)ws;    // 8,388,608 B
  int2*           coords = (int2*)(ws + 8388608);            //   524,288 B
  unsigned short* Bmat   = (unsigned short*)(ws + 8912896);  // 1,179,648 B

  k_convw<<<576, 256, 0, stream>>>(cw, Bmat);
  k_accum2<<<dim3(16, 64), 256, 0, stream>>>(seg, partials);
  k_coords2<<<256, 256, 0, stream>>>(partials, coords);
  k_gemmf<<<768, 512, 0, stream>>>(img, coords, Bmat, out);
}

// Round 7
// 176.946 us; speedup vs baseline: 2.4508x; 2.4508x over previous
//
#include <hip/hip_runtime.h>
#include <hip/hip_bf16.h>
#include <stdint.h>

// Problem constants (fixed by setup_inputs)
#define B_   64
#define H_   512
#define W_   512
#define S_N  1024      // n_segments
#define E_N  768       // embed_dim
#define K_N  768       // C*box*box = 3*16*16
#define HALF 8
#define NT   12        // K tiles of BK=64

typedef short bf16x8 __attribute__((ext_vector_type(8)));
typedef float f32x4  __attribute__((ext_vector_type(4)));

__device__ __forceinline__ unsigned short f2bf(float f) {
  union { float f; unsigned u; } v; v.f = f;
  unsigned u = v.u;
  u += 0x7FFF + ((u >> 16) & 1);   // RNE
  return (unsigned short)(u >> 16);
}

// ---------------- Phase 1: per-(b,s) packed sums, NO global atomics -----------
// [y:24 @39 | x:24 @15 | cnt:15 @0]. Incremental pack: p0 is int4-aligned and
// W=512 -> p0%512 <= 508, so j=0..3 never crosses a row; x-field low bits are
// 0 mod 4 -> base + (j<<15) == base | (j<<15), carry-free.
__global__ void k_accum2(const int* __restrict__ seg,
                         unsigned long long* __restrict__ partials) {
  __shared__ unsigned long long ls[S_N];
  const int tid = threadIdx.x;
  const int xblk = blockIdx.x;   // 0..15
  const int b = blockIdx.y;
  for (int i = tid; i < S_N; i += 256) ls[i] = 0ULL;
  __syncthreads();
  const int pix0 = xblk * 16384;
  const int4* segb = (const int4*)(seg + (size_t)b * (H_ * W_) + pix0);
  for (int it = 0; it < 16; ++it) {
    int4 s4 = segb[it * 256 + tid];
    int p0 = pix0 + (it * 256 + tid) * 4;
    unsigned long long base = ((unsigned long long)(unsigned)(p0 >> 9) << 39)
                            | ((unsigned long long)(unsigned)(p0 & (W_ - 1)) << 15)
                            | 1ULL;
    #pragma unroll
    for (int j = 0; j < 4; ++j) {
      int s = (&s4.x)[j];
      s = ((unsigned)s < S_N) ? s : 0;
      atomicAdd(&ls[s], base + ((unsigned long long)j << 15));
    }
  }
  __syncthreads();
  unsigned long long* gp = partials + ((size_t)b * 16 + xblk) * S_N;
  for (int s = tid; s < S_N; s += 256) gp[s] = ls[s];
}

// -------- Phase 2 (merged): conv_w fp32->bf16 (blocks 0..575) +
//          partial-reduce/centroid/floor (blocks 576..831) --------------------
__global__ void k_prep(const float* __restrict__ w, unsigned short* __restrict__ wb,
                       const unsigned long long* __restrict__ partials,
                       int2* __restrict__ coords) {
  const int bid = blockIdx.x;
  const int tid = threadIdx.x;
  if (bid < 576) {
    int idx = bid * 256 + tid;                  // 147,456 float4s
    float4 v = ((const float4*)w)[idx];
    ushort4 o;
    o.x = f2bf(v.x); o.y = f2bf(v.y); o.z = f2bf(v.z); o.w = f2bf(v.w);
    ((ushort4*)wb)[idx] = o;
  } else {
    int m = (bid - 576) * 256 + tid;            // 65536 = B*S
    int b = m >> 10, s = m & (S_N - 1);
    unsigned sx = 0, sy = 0, c = 0;
    #pragma unroll
    for (int x = 0; x < 16; ++x) {
      unsigned long long v = partials[((size_t)b * 16 + x) * S_N + s];
      c  += (unsigned)(v & 0x7FFFULL);
      sx += (unsigned)((v >> 15) & 0xFFFFFFULL);
      sy += (unsigned)(v >> 39);
    }
    float xc = 0.f, yc = 0.f;
    if (c > 0) {
      float cf = (float)c;
      xc = (float)sx / cf;   // IEEE f32 div of exact ints == reference
      yc = (float)sy / cf;
    }
    coords[m] = make_int2((int)floorf(xc), (int)floorf(yc));
  }
}

// ---------------- Phase 3a: COALESCED patch gather -> bf16 A[M][K] ------------
// 16-lane group <-> one patch; lane = x-offset within the 16-wide row. Per load
// instruction a wave touches 4 patch rows (~6-8 cache lines) instead of the old
// 48-64 scattered lines -> ~8x fewer memory transactions (the r6 lesson).
__global__ __launch_bounds__(256) void k_patch2(const float* __restrict__ img,
                                                const int2* __restrict__ coords,
                                                unsigned short* __restrict__ A) {
  const int g  = threadIdx.x >> 4;    // 0..15 : patch slot in block
  const int lx = threadIdx.x & 15;    // x-offset lane
  const int m  = blockIdx.x * 16 + g;
  const int2 cc = coords[m];
  const int b  = m >> 10;
  const int x  = cc.x - HALF + lx;
  const int y0 = cc.y - HALF;
  const bool xok = (unsigned)x < W_;
  const int xs = xok ? x : 0;
  const float* ib = img + (size_t)b * 3 * H_ * W_;
  unsigned short* Am = A + (size_t)m * K_N + lx;
  #pragma unroll
  for (int r = 0; r < 48; ++r) {      // r = c*16 + h
    const int y = y0 + (r & 15);
    const bool ok = xok && ((unsigned)y < H_);
    const int ys = ((unsigned)y < H_) ? y : 0;
    float v = ib[(((r >> 4) << 9) + ys) * W_ + xs];
    v = ok ? v : 0.f;
    Am[r * 16] = f2bf(v);
  }
}

// ---------------- Phase 3b: 256x256 8-phase bf16 MFMA GEMM (r5-identical) -----
__global__ __launch_bounds__(512) void k_gemm8(
    const unsigned short* __restrict__ Amat,
    const unsigned short* __restrict__ Bmat,
    float* __restrict__ out) {
  __shared__ unsigned short As[2][256 * 64];
  __shared__ unsigned short Bs[2][256 * 64];
  const int tid  = threadIdx.x;
  const int wave = tid >> 6;
  const int lane = tid & 63;

  // bijective XCD remap: 768 blocks = 8 XCDs x 96
  const int virt = (blockIdx.x & 7) * 96 + (blockIdx.x >> 3);
  const int bm = virt / 3;
  const int bn = virt - bm * 3;
  const int gm0 = bm * 256;
  const int gn0 = bn * 256;

  const int wr = wave >> 2;          // 0..1
  const int wc = wave & 3;           // 0..3
  const int rlo  = lane & 15;
  const int rsel = lane & 7;
  const int sub  = lane >> 4;        // 0..3
  int swz[2];
  swz[0] = ((0 + sub) ^ rsel) * 8;   // shorts offset, kk=0
  swz[1] = ((4 + sub) ^ rsel) * 8;   // kk=1

  const int srow = lane >> 3;             // row within 8-row group
  const int sch  = (lane & 7) ^ srow;     // pre-swizzled source chunk

  f32x4 acc[8][4];
  #pragma unroll
  for (int i = 0; i < 8; ++i)
    #pragma unroll
    for (int j = 0; j < 4; ++j)
      acc[i][j] = (f32x4){0.f, 0.f, 0.f, 0.f};

  auto stageA = [&](int buf, int mh, int k0) {
    #pragma unroll
    for (int l = 0; l < 2; ++l) {
      int idx = wave * 2 + l;                                // 0..15
      int rowbase = mh * 64 + (idx >> 3) * 128 + (idx & 7) * 8;
      const unsigned short* g = Amat + (size_t)(gm0 + rowbase + srow) * K_N + k0 + sch * 8;
      __builtin_amdgcn_global_load_lds((const __attribute__((address_space(1))) void*)g,
        (__attribute__((address_space(3))) void*)&As[buf][rowbase * 64], 16, 0, 0);
    }
  };
  auto stageB = [&](int buf, int nh, int k0) {
    #pragma unroll
    for (int l = 0; l < 2; ++l) {
      int idx = wave * 2 + l;
      int rowbase = (idx >> 2) * 64 + nh * 32 + (idx & 3) * 8;
      const unsigned short* g = Bmat + (size_t)(gn0 + rowbase + srow) * K_N + k0 + sch * 8;
      __builtin_amdgcn_global_load_lds((const __attribute__((address_space(1))) void*)g,
        (__attribute__((address_space(3))) void*)&Bs[buf][rowbase * 64], 16, 0, 0);
    }
  };

  bf16x8 a[4][2], b[2][2];

#define LOAD_A(BUF, MH) \
  _Pragma("unroll") for (int mi = 0; mi < 4; ++mi) \
  _Pragma("unroll") for (int kk = 0; kk < 2; ++kk) \
    a[mi][kk] = *(const bf16x8*)&As[BUF][(wr * 128 + (MH) * 64 + mi * 16 + rlo) * 64 + swz[kk]];
#define LOAD_B(BUF, NH) \
  _Pragma("unroll") for (int ni = 0; ni < 2; ++ni) \
  _Pragma("unroll") for (int kk = 0; kk < 2; ++kk) \
    b[ni][kk] = *(const bf16x8*)&Bs[BUF][(wc * 64 + (NH) * 32 + ni * 16 + rlo) * 64 + swz[kk]];
#define MFMA_Q(MI0, NI0) \
  __builtin_amdgcn_s_setprio(1); \
  _Pragma("unroll") for (int mi = 0; mi < 4; ++mi) \
  _Pragma("unroll") for (int ni = 0; ni < 2; ++ni) \
  _Pragma("unroll") for (int kk = 0; kk < 2; ++kk) \
    acc[(MI0) + mi][(NI0) + ni] = __builtin_amdgcn_mfma_f32_16x16x32_bf16( \
        a[mi][kk], b[ni][kk], acc[(MI0) + mi][(NI0) + ni], 0, 0, 0); \
  __builtin_amdgcn_s_setprio(0);
#define SYNC_MFMA \
  __builtin_amdgcn_s_barrier(); \
  asm volatile("s_waitcnt lgkmcnt(0)" ::: "memory"); \
  __builtin_amdgcn_sched_barrier(0);
#define ENDPH __builtin_amdgcn_s_barrier();

  // Prologue: tile0 fully into buf0; tile1's hA0,hB1 into buf1 (staged last).
  stageA(0, 0, 0); stageA(0, 1, 0); stageB(0, 0, 0); stageB(0, 1, 0);
  stageA(1, 0, 64); stageB(1, 1, 64);
  asm volatile("s_waitcnt vmcnt(4)" ::: "memory");   // buf0 landed
  __builtin_amdgcn_s_barrier();

  for (int i = 0; i < 6; ++i) {
    const int kB = (2 * i + 1) * 64;
    const int kC = (2 * i + 2) * 64;
    const int kD = (2 * i + 3) * 64;
    const bool sC = (2 * i + 2) < NT;
    const bool sD = (2 * i + 3) < NT;
    // P1: Q1 of tile 2i (buf0)
    LOAD_A(0, 0); LOAD_B(0, 0);
    stageB(1, 0, kB);                 // buf1.hB0 <- tile 2i+1 (freed prev P8)
    SYNC_MFMA; MFMA_Q(0, 0); ENDPH;
    // P2
    LOAD_B(0, 1);
    stageA(1, 1, kB);                 // buf1.hA1 <- tile 2i+1 (freed prev P8)
    SYNC_MFMA; MFMA_Q(0, 2); ENDPH;
    // P3
    LOAD_A(0, 1);
    if (sC) stageA(0, 0, kC);         // buf0.hA0 <- tile 2i+2 (freed P2)
    SYNC_MFMA; MFMA_Q(4, 2); ENDPH;
    // P4
    LOAD_B(0, 0);
    if (sC) stageB(0, 1, kC);         // buf0.hB1 <- tile 2i+2 (freed P3)
    asm volatile("s_waitcnt vmcnt(4)" ::: "memory");  // tile 2i+1 fully landed
    SYNC_MFMA; MFMA_Q(4, 0); ENDPH;
    // P5: Q1 of tile 2i+1 (buf1)
    LOAD_A(1, 0); LOAD_B(1, 0);
    if (sC) stageB(0, 0, kC);         // buf0.hB0 (freed P4)
    SYNC_MFMA; MFMA_Q(0, 0); ENDPH;
    // P6
    LOAD_B(1, 1);
    if (sC) stageA(0, 1, kC);         // buf0.hA1 (freed P4)
    SYNC_MFMA; MFMA_Q(0, 2); ENDPH;
    // P7
    LOAD_A(1, 1);
    if (sD) stageA(1, 0, kD);         // buf1.hA0 <- tile 2i+3 (freed P6)
    SYNC_MFMA; MFMA_Q(4, 2); ENDPH;
    // P8
    LOAD_B(1, 0);
    if (sD) stageB(1, 1, kD);         // buf1.hB1 <- tile 2i+3 (freed P7)
    asm volatile("s_waitcnt vmcnt(4)" ::: "memory");  // tile 2i+2 fully landed
    SYNC_MFMA; MFMA_Q(4, 0); ENDPH;
  }

  // Epilogue: C/D layout col=lane&15, row=(lane>>4)*4+reg
  const int row0 = gm0 + wr * 128 + (lane >> 4) * 4;
  const int col0 = gn0 + wc * 64 + (lane & 15);
  #pragma unroll
  for (int mi = 0; mi < 8; ++mi)
    #pragma unroll
    for (int ni = 0; ni < 4; ++ni)
      #pragma unroll
      for (int r = 0; r < 4; ++r)
        out[(size_t)(row0 + mi * 16 + r) * E_N + (col0 + ni * 16)] = acc[mi][ni][r];
#undef LOAD_A
#undef LOAD_B
#undef MFMA_Q
#undef SYNC_MFMA
#undef ENDPH
}

extern "C" void kernel_launch(void* const* d_in, const int* in_sizes, int n_in,
                              void* d_out, int out_size, void* d_ws, size_t ws_size,
                              hipStream_t stream) {
  const float* img = (const float*)d_in[0];
  const int*   seg = (const int*)d_in[1];
  const float* cw  = (const float*)d_in[2];
  float* out = (float*)d_out;
  char* ws = (char*)d_ws;

  unsigned long long* partials = (unsigned long long*)ws;    // 8,388,608 B
  int2*           coords = (int2*)(ws + 8388608);            //   524,288 B
  unsigned short* Bmat   = (unsigned short*)(ws + 8912896);  // 1,179,648 B
  unsigned short* Amat   = (unsigned short*)(ws + 10092544); // 100,663,296 B

  k_accum2<<<dim3(16, 64), 256, 0, stream>>>(seg, partials);
  k_prep<<<832, 256, 0, stream>>>(cw, Bmat, partials, coords);
  k_patch2<<<4096, 256, 0, stream>>>(img, coords, Amat);
  k_gemm8<<<768, 512, 0, stream>>>(Amat, Bmat, out);
}